// Round 12
// baseline (215.087 us; speedup 1.0000x reference)
//
#include <hip/hip_runtime.h>

#define IMG   512
#define NA    90
#define DET   729
#define NPIX  (IMG*IMG)
#define HW    514            // halo'd NHWC width/height
#define QW    514            // quad image width
#define HBELEMS (HW*HW*32)   // elems per halo'd NHWC bf16 buffer

typedef __attribute__((ext_vector_type(8))) short     bf16x8;
typedef __attribute__((ext_vector_type(8))) unsigned short ushort8;
typedef __attribute__((ext_vector_type(4))) float     f32x4;

__device__ __forceinline__ unsigned short f2b(float f) {
    unsigned int u = __builtin_bit_cast(unsigned int, f);
    return (unsigned short)((u + 0x7FFFu + ((u >> 16) & 1u)) >> 16);
}
__device__ __forceinline__ float b2f(unsigned short h) {
    return __builtin_bit_cast(float, (unsigned int)h << 16);
}

// ---------------- prep0: trig (blk 0) + f32x4 quad image (blks 1..1033) + sino zero (rest) ----------------
__global__ void prep0_k(const float* __restrict__ theta, const float* __restrict__ img,
                        float* __restrict__ trig, float4* __restrict__ quad4,
                        float* __restrict__ sino) {
    if (blockIdx.x == 0) {
        int i = threadIdx.x;
        if (i < NA) {
            float t = theta[i];
            trig[2*i]   = cosf(t);
            trig[2*i+1] = sinf(t);
        }
        return;
    }
    if (blockIdx.x <= 1033) {
        int q = (blockIdx.x - 1) * 256 + threadIdx.x;
        if (q >= QW*QW) return;
        int qy = q / QW, qx = q - qy*QW;
        auto val = [&](int r, int c) -> float {
            return (r >= 1 && r <= 512 && c >= 1 && c <= 512) ? img[((r-1) << 9) + (c-1)] : 0.f;
        };
        quad4[q] = make_float4(val(qy, qx), val(qy, qx+1), val(qy+1, qx), val(qy+1, qx+1));
        return;
    }
    int z = (blockIdx.x - 1034) * 256 + threadIdx.x;
    if (z < NA*DET) sino[z] = 0.f;
}

// ---------------- radon forward: f32x4 ring tile, maskless clamped loop ----------------
// LDS 35x35 f32x4 + 1 zero slot. Interior (r,c) in [1,32] = quad4[Y0+r-1][X0+c-1];
// ring rows/cols 0,33,34 zero (ownership: out-of-tile samples interp zeros -> exact 0).
// Clamp redirects any wild index to the zero slot; ix=35 / ix=-1 wrap onto ring-zero columns.
__global__ __launch_bounds__(256) void radon_tile_k(const float4* __restrict__ quad4,
        const float* __restrict__ trig, float* __restrict__ sino) {
    __shared__ float4 tl4[1226];
    int b  = blockIdx.x;
    int tq = b % 289;
    int g  = b / 289;                  // angle group: angles 4g..4g+3
    int tx = tq % 17, ty = tq / 17;
    int X0 = tx*32, Y0 = ty*32;        // quad-space tile origin
    int tid = threadIdx.x;

    for (int e = tid; e < 1226; e += 256) {
        float4 v = make_float4(0.f, 0.f, 0.f, 0.f);
        int r = e / 35, c = e - r*35;                 // e=1225 -> r=35: stays zero
        if (r >= 1 && r <= 32 && c >= 1 && c <= 32) {
            int gy = Y0 + r - 1, gx = X0 + c - 1;
            if (gy < QW && gx < QW) v = quad4[gy*QW + gx];
        }
        tl4[e] = v;
    }
    __syncthreads();

    int w = tid >> 6, lane = tid & 63;
    int a = g*4 + w;
    if (a >= NA) return;
    float cs = trig[2*a], sn = trig[2*a+1];   // sn >= 0 for theta in [0,pi)

    float fX0 = (float)X0 - 1.0f;      // px valid in [fX0, fX0+32)
    float fY0 = (float)Y0 - 1.0f;

    // detector range crossing this tile
    float cx0 = fX0 - 255.5f, cx1 = cx0 + 32.0f;
    float cy0 = fY0 - 255.5f, cy1 = cy0 + 32.0f;
    float sdmin = fminf(cx0*cs, cx1*cs) + fminf(cy0*sn, cy1*sn);
    float sdmax = fmaxf(cx0*cs, cx1*cs) + fmaxf(cy0*sn, cy1*sn);
    int dmin = (int)ceilf(sdmin + 364.0f) - 1; if (dmin < 0) dmin = 0;
    int dmax = (int)floorf(sdmax + 364.0f) + 1; if (dmax > DET-1) dmax = DET-1;
    int d = dmin + lane;
    if (d > dmax) return;

    float sd = (float)d - 364.0f;
    float bx = 255.5f + sd*cs, by = 255.5f + sd*sn;
    // sj slabs: px = bx - sj*sn in [fX0,fX0+32); py = by + sj*cs in [fY0,fY0+32)
    float lo = -365.0f, hi = 365.0f;
    if (sn > 1e-7f) {
        float inv = 1.0f / sn;
        lo = (bx - (fX0 + 32.0f)) * inv;
        hi = (bx - fX0) * inv;
    } else if (bx < fX0 || bx >= fX0 + 32.0f) return;
    if (fabsf(cs) > 1e-7f) {
        float inv = 1.0f / cs;
        float s1 = (fY0 - by) * inv, s2 = (fY0 + 32.0f - by) * inv;
        lo = fmaxf(lo, fminf(s1, s2));
        hi = fminf(hi, fmaxf(s1, s2));
    } else if (by < fY0 || by >= fY0 + 32.0f) return;
    int jlo = (int)ceilf(lo + 364.0f) - 1; if (jlo < 0) jlo = 0;
    int jhi = (int)floorf(hi + 364.0f) + 1; if (jhi > DET-1) jhi = DET-1;
    if (jlo > jhi) return;

    // ring-local coords: owned samples land at ix,iy in [1,32]; extensions in ring
    float sj = (float)jlo - 364.0f;
    float px2 = bx - sj*sn - fX0 + 1.0f;
    float py2 = by + sj*cs - fY0 + 1.0f;
    float acc = 0.f;
    #pragma unroll 2
    for (int j = jlo; j <= jhi; ++j) {
        float fpx = floorf(px2), fpy = floorf(py2);
        int ix = (int)fpx, iy = (int)fpy;
        float fx = px2 - fpx, fy = py2 - fpy;
        unsigned ba = ((unsigned)(iy*35 + ix)) * 16u;
        if (ba > 19584u) ba = 19600u;              // zero slot: contribution exactly 0
        float4 q = *(const float4*)((const char*)tl4 + ba);
        float top = fmaf(fx, q.y - q.x, q.x);
        float bot = fmaf(fx, q.w - q.z, q.z);
        acc += fmaf(fy, bot - top, top);
        px2 -= sn; py2 += cs;
    }
    if (acc != 0.f) atomicAdd(&sino[a*DET + d], acc);
}

// ---------------- ramp filter (direct conv == FFT path) + subtract measurement ----------------
__global__ __launch_bounds__(256) void filter_k(const float* __restrict__ sino,
        const float* __restrict__ meas, float* __restrict__ diff) {
    __shared__ float prow[DET + 2*728];
    __shared__ float invsq[364];
    int a = blockIdx.x / 3, seg = blockIdx.x - 3*a;
    for (int t = threadIdx.x; t < DET + 2*728; t += 256)
        prow[t] = (t >= 728 && t < 728 + DET) ? sino[a*DET + (t - 728)] : 0.f;
    const float cc = -2.0f / (3.14159265358979323846f * 3.14159265358979323846f);
    for (int k = threadIdx.x; k < 364; k += 256) {
        float dlt = (float)(2*k + 1);
        invsq[k] = cc / (dlt * dlt);
    }
    __syncthreads();
    const float scale = 3.14159265358979323846f / 180.0f;  // pi/(2*90)
    int i = seg*243 + threadIdx.x;
    if (threadIdx.x < 243) {
        const float* p = prow + 728 + i;
        float acc = 0.5f * p[0];
        #pragma unroll 4
        for (int k = 0; k < 364; k++) {
            int dlt = 2*k + 1;
            acc += (p[-dlt] + p[dlt]) * invsq[k];
        }
        diff[a*DET + i] = acc * scale - meas[a*DET + i];
    }
}

// ---------------- build float2 pairs (diff[i], diff[i+1]) for backprojection ----------------
__global__ void pair_k(const float* __restrict__ diff, float2* __restrict__ pair) {
    int i = blockIdx.x * 256 + threadIdx.x;
    if (i >= NA*DET) return;
    int col = i - (i / DET) * DET;
    float b = (col == DET-1) ? 0.f : diff[i + 1];
    pair[i] = make_float2(diff[i], b);
}

// ---------------- backprojection fused with x_input = x - lambda*bp ----------------
__global__ __launch_bounds__(256) void backproj_k(const float2* __restrict__ pair,
        const float* __restrict__ trig, const float* __restrict__ x,
        const float* __restrict__ lam, float* __restrict__ xin) {
    int pix = blockIdx.x * 256 + threadIdx.x;
    float X = (float)(pix & 511) - 255.5f;
    float Y = (float)(pix >> 9) - 255.5f;
    float acc = 0.f;
    for (int a = 0; a < NA; a++) {
        float pos = X*trig[2*a] + Y*trig[2*a+1] + 364.0f;
        if (pos >= 0.f && pos <= 728.f) {
            int i0 = (int)pos;
            if (i0 > 727) i0 = 727;
            float w = pos - (float)i0;
            float2 p = pair[a*DET + i0];
            acc += p.x + w*(p.y - p.x);
        }
    }
    xin[pix] = x[pix] - lam[0] * acc;
}

// ---------------- prep1: halo zeroing + convM weights + convG padded weights ----------------
__global__ void prep1_k(unsigned short* __restrict__ hb0, size_t hbstride_elems,
                        const float* __restrict__ w0, const float* __restrict__ w1,
                        const float* __restrict__ w2, const float* __restrict__ w3,
                        const float* __restrict__ wg4,
                        unsigned short* __restrict__ wbuf) {
    int t = blockIdx.x * 256 + threadIdx.x;
    if (t < 4*2052) {
        int b = t / 2052, r = t - b*2052;
        int py, px;
        if      (r < 514)  { py = 0;            px = r; }
        else if (r < 1028) { py = 513;          px = r - 514; }
        else if (r < 1540) { py = r - 1028 + 1; px = 0; }
        else               { py = r - 1540 + 1; px = 513; }
        unsigned short* p = hb0 + b*hbstride_elems + ((size_t)py*HW + px)*32;
        uint4 z = make_uint4(0,0,0,0);
        ((uint4*)p)[0] = z; ((uint4*)p)[1] = z; ((uint4*)p)[2] = z; ((uint4*)p)[3] = z;
        return;
    }
    int tid = t - 4*2052;
    if (tid < 4*9216) {
        int L = tid / 9216, r = tid - L*9216;
        int tt = r >> 10, o = (r >> 5) & 31, i = r & 31;
        const float* s = (L == 0) ? w0 : (L == 1) ? w1 : (L == 2) ? w2 : w3;
        wbuf[tid] = f2b(s[o*288 + i*9 + tt]);
        return;
    }
    int gid = tid - 4*9216;                 // wG padded: [tap][16 oc][32 ic], oc0 real
    if (gid >= 9*512) return;
    int tt = gid / 512, r = gid - tt*512;
    int o = r >> 5, i = r & 31;
    wbuf[4*9216 + gid] = (o == 0) ? f2b(wg4[i*9 + tt]) : (unsigned short)0;
}

// ---------------- conv_D: 1 -> 32, f32 direct; writes bf16 NHWC halo'd ----------------
__global__ __launch_bounds__(256) void convD_k(const float* __restrict__ xin,
        const float* __restrict__ wD, unsigned short* __restrict__ out_nhwc) {
    int pix = blockIdx.x * 256 + threadIdx.x;
    int y = pix >> 9, x = pix & 511;
    float v[9];
    #pragma unroll
    for (int dy = -1; dy <= 1; dy++)
        #pragma unroll
        for (int dx = -1; dx <= 1; dx++) {
            int yy = y + dy, xx = x + dx;
            v[(dy+1)*3 + dx+1] = (yy >= 0 && yy < 512 && xx >= 0 && xx < 512)
                                 ? xin[(yy << 9) + xx] : 0.f;
        }
    unsigned int packed[16];
    #pragma unroll
    for (int oc = 0; oc < 32; ++oc) {
        float acc = 0.f;
        #pragma unroll
        for (int t = 0; t < 9; t++) acc = fmaf(v[t], wD[oc*9 + t], acc);
        unsigned int b = f2b(acc);
        if (oc & 1) packed[oc >> 1] |= b << 16; else packed[oc >> 1] = b;
    }
    uint4* dst = (uint4*)(out_nhwc + ((size_t)(y+1)*HW + (x+1))*32);
    dst[0] = make_uint4(packed[0],  packed[1],  packed[2],  packed[3]);
    dst[1] = make_uint4(packed[4],  packed[5],  packed[6],  packed[7]);
    dst[2] = make_uint4(packed[8],  packed[9],  packed[10], packed[11]);
    dst[3] = make_uint4(packed[12], packed[13], packed[14], packed[15]);
}

// ---------------- MFMA conv 32->32: 4-row blocked, dx-outer (A resident = 24 VGPR), occ=4 ----------------
// MODE: 0 plain->out0 | 1 relu->out0 | 2 dual: raw->out0, softthr->out1
//       | 3 symloss: - aux(bf16 NHWC) -> s1,s2 (f32 NCHW)
template<int MODE>
__global__ __launch_bounds__(256, 4) void convM_k(const unsigned short* __restrict__ in,
        const unsigned short* __restrict__ wb,
        unsigned short* __restrict__ out0, unsigned short* __restrict__ out1,
        const float* __restrict__ thr_p,
        const unsigned short* __restrict__ aux, float* __restrict__ s1, float* __restrict__ s2) {
    int wv   = threadIdx.x >> 6;
    int lane = threadIdx.x & 63;
    int bx = blockIdx.x & 31, by = blockIdx.x >> 5;
    int x0 = bx*16;
    int yb = by*16 + wv*4;        // first output row of this wave
    int lpix = lane & 15;
    int k8   = (lane >> 4) * 8;

    f32x4 acc[2][4];
    #pragma unroll
    for (int ob = 0; ob < 2; ob++)
        #pragma unroll
        for (int o = 0; o < 4; o++) acc[ob][o] = (f32x4){0.f,0.f,0.f,0.f};

    const short* base = (const short*)in + ((size_t)yb*HW + (x0 + lpix))*32 + k8;

    #pragma unroll
    for (int dx = 0; dx < 3; ++dx) {
        bf16x8 A2[3][2];
        #pragma unroll
        for (int dy = 0; dy < 3; ++dy)
            #pragma unroll
            for (int ob = 0; ob < 2; ob++)
                A2[dy][ob] = *(const bf16x8*)(wb + (dy*3+dx)*1024 + (ob*16 + lpix)*32 + k8);
        #pragma unroll
        for (int r = 0; r < 6; ++r) {
            bf16x8 B = *(const bf16x8*)(base + ((size_t)r*HW + dx)*32);
            #pragma unroll
            for (int dy = 0; dy < 3; ++dy) {
                int o = r - dy;
                if (o >= 0 && o < 4) {
                    acc[0][o] = __builtin_amdgcn_mfma_f32_16x16x32_bf16(A2[dy][0], B, acc[0][o], 0,0,0);
                    acc[1][o] = __builtin_amdgcn_mfma_f32_16x16x32_bf16(A2[dy][1], B, acc[1][o], 0,0,0);
                }
            }
        }
    }

    int prow = (lane >> 4) * 4;
    float thr = (MODE == 2) ? thr_p[0] : 0.f;
    #pragma unroll
    for (int ob = 0; ob < 2; ob++)
        #pragma unroll
        for (int o = 0; o < 4; o++) {
            f32x4 a = acc[ob][o];
            if (MODE == 3) {
                size_t aoff = ((size_t)(yb+o+1)*HW + (x0 + 1 + lpix))*32 + ob*16 + prow;
                ushort4 av = *(const ushort4*)(aux + aoff);
                int pix = ((yb+o) << 9) + x0 + lpix;
                float w0v = a[0] - b2f(av.x);
                float w1v = a[1] - b2f(av.y);
                float w2v = a[2] - b2f(av.z);
                float w3v = a[3] - b2f(av.w);
                int ocb = ob*16 + prow;
                s1[(size_t)(ocb+0)*NPIX + pix] = w0v; s2[(size_t)(ocb+0)*NPIX + pix] = w0v;
                s1[(size_t)(ocb+1)*NPIX + pix] = w1v; s2[(size_t)(ocb+1)*NPIX + pix] = w1v;
                s1[(size_t)(ocb+2)*NPIX + pix] = w2v; s2[(size_t)(ocb+2)*NPIX + pix] = w2v;
                s1[(size_t)(ocb+3)*NPIX + pix] = w3v; s2[(size_t)(ocb+3)*NPIX + pix] = w3v;
            } else {
                size_t off = ((size_t)(yb+o+1)*HW + (x0 + 1 + lpix))*32 + ob*16 + prow;
                if (MODE == 1) {
                    #pragma unroll
                    for (int r2 = 0; r2 < 4; r2++) a[r2] = fmaxf(a[r2], 0.f);
                }
                *(ushort4*)(out0 + off) = make_ushort4(f2b(a[0]), f2b(a[1]), f2b(a[2]), f2b(a[3]));
                if (MODE == 2) {
                    float st[4];
                    #pragma unroll
                    for (int r2 = 0; r2 < 4; r2++)
                        st[r2] = copysignf(fmaxf(fabsf(a[r2]) - thr, 0.f), a[r2]);
                    *(ushort4*)(out1 + off) = make_ushort4(f2b(st[0]), f2b(st[1]), f2b(st[2]), f2b(st[3]));
                }
            }
        }
}

// ---------------- conv_G via MFMA: 32 -> 1 (A row 0 = wG), fused + xin ----------------
__global__ __launch_bounds__(256) void convGM_k(const unsigned short* __restrict__ in,
        const unsigned short* __restrict__ wg,      // [tap][16][32], oc0 real
        const float* __restrict__ xin, float* __restrict__ out) {
    int wid  = threadIdx.x >> 6;
    int lane = threadIdx.x & 63;
    int by = blockIdx.x >> 3, bx = blockIdx.x & 7;
    int y  = by*4 + wid;
    int x0 = bx*64;
    int lpix = lane & 15;
    int k8   = (lane >> 4) * 8;

    bf16x8 A[9];
    #pragma unroll
    for (int t = 0; t < 9; t++)
        A[t] = *(const bf16x8*)(wg + t*512 + lpix*32 + k8);

    f32x4 acc[4];
    #pragma unroll
    for (int p = 0; p < 4; p++) acc[p] = (f32x4){0.f,0.f,0.f,0.f};

    const short* base = (const short*)in + ((size_t)(y+1)*HW + (x0+1) + lpix)*32 + k8;
    #pragma unroll
    for (int dy = -1; dy <= 1; dy++)
        #pragma unroll
        for (int dx = -1; dx <= 1; dx++) {
            int t = (dy+1)*3 + (dx+1);
            const short* bp = base + (dy*HW + dx)*32;
            #pragma unroll
            for (int p = 0; p < 4; p++) {
                bf16x8 B = *(const bf16x8*)(bp + p*16*32);
                acc[p] = __builtin_amdgcn_mfma_f32_16x16x32_bf16(A[t], B, acc[p], 0,0,0);
            }
        }

    if (lane < 16) {
        #pragma unroll
        for (int p = 0; p < 4; p++) {
            int pix = (y << 9) + x0 + p*16 + lane;
            out[pix] = acc[p][0] + xin[pix];
        }
    }
}

extern "C" void kernel_launch(void* const* d_in, const int* in_sizes, int n_in,
                              void* d_out, int out_size, void* d_ws, size_t ws_size,
                              hipStream_t stream) {
    const float* x     = (const float*)d_in[0];
    const float* theta = (const float*)d_in[1];
    const float* meas  = (const float*)d_in[2];
    const float* lam   = (const float*)d_in[3];
    const float* thr   = (const float*)d_in[4];
    const float* wD    = (const float*)d_in[5];
    const float* w1f   = (const float*)d_in[6];
    const float* w2f   = (const float*)d_in[7];
    const float* w1b   = (const float*)d_in[8];
    const float* w2b   = (const float*)d_in[9];
    const float* wG    = (const float*)d_in[10];

    char* ws = (char*)d_ws;
    const size_t HBB = (size_t)HBELEMS * 2;          // bytes per halo'd bf16 buffer
    unsigned short* HB1 = (unsigned short*)(ws);
    unsigned short* HB2 = (unsigned short*)(ws + HBB);
    unsigned short* HB3 = (unsigned short*)(ws + 2*HBB);
    unsigned short* HB4 = (unsigned short*)(ws + 3*HBB);
    // radon scratch aliases: sino/diff/pair in HB2 (dead until h1), quad4 (4.03MB) in HB3 (dead until xf;
    // HB3 halo ring is zeroed by prep1 AFTER radon consumes quad4 — ordering is load-bearing!)
    float*  sino  = (float*)(ws + HBB);
    float*  diff  = (float*)(ws + HBB + 262464);
    float2* dpair = (float2*)(ws + HBB + 524928);
    float4* quad4 = (float4*)(ws + 2*HBB);
    float* xin  = (float*)(ws + 4*HBB);
    float* trig = (float*)(ws + 4*HBB + 1048576);
    unsigned short* wbuf = (unsigned short*)(ws + 4*HBB + 1049600);
    unsigned short* wgbuf = wbuf + 4*9216;

    float* P  = (float*)d_out;        // x_pred  (NPIX)
    float* S1 = P + NPIX;             // symloss #1 (32*NPIX)
    float* S2 = S1 + 32*NPIX;         // symloss #2 (32*NPIX)

    prep0_k<<<1 + 1033 + 257, 256, 0, stream>>>(theta, x, trig, quad4, sino);
    radon_tile_k<<<289*23, 256, 0, stream>>>(quad4, trig, sino);
    filter_k<<<NA*3, 256, 0, stream>>>(sino, meas, diff);
    pair_k<<<(NA*DET + 255)/256, 256, 0, stream>>>(diff, dpair);
    backproj_k<<<NPIX/256, 256, 0, stream>>>(dpair, trig, x, lam, xin);
    prep1_k<<<(4*2052 + 4*9216 + 9*512 + 255)/256, 256, 0, stream>>>(HB1, HBELEMS,
                                             w1f, w2f, w1b, w2b, wG, wbuf);

    convD_k<<<NPIX/256, 256, 0, stream>>>(xin, wD, HB1);                           // x_D -> HB1 (persists)
    convM_k<1><<<1024, 256, 0, stream>>>(HB1, wbuf + 0*9216, HB2, nullptr,
                                         nullptr, nullptr, nullptr, nullptr);      // h1 -> HB2
    convM_k<2><<<1024, 256, 0, stream>>>(HB2, wbuf + 1*9216, HB3, HB4,
                                         thr, nullptr, nullptr, nullptr);          // xf -> HB3, st -> HB4
    convM_k<1><<<1024, 256, 0, stream>>>(HB4, wbuf + 2*9216, HB2, nullptr,
                                         nullptr, nullptr, nullptr, nullptr);      // h2 -> HB2
    convM_k<0><<<1024, 256, 0, stream>>>(HB2, wbuf + 3*9216, HB4, nullptr,
                                         nullptr, nullptr, nullptr, nullptr);      // xb -> HB4
    convGM_k<<<1024, 256, 0, stream>>>(HB4, wgbuf, xin, P);                        // x_pred
    convM_k<1><<<1024, 256, 0, stream>>>(HB3, wbuf + 2*9216, HB2, nullptr,
                                         nullptr, nullptr, nullptr, nullptr);      // h3 -> HB2
    convM_k<3><<<1024, 256, 0, stream>>>(HB2, wbuf + 3*9216, nullptr, nullptr,
                                         nullptr, HB1, S1, S2);                    // symloss
}

// Round 13
// 212.785 us; speedup vs baseline: 1.0108x; 1.0108x over previous
//
#include <hip/hip_runtime.h>

#define IMG   512
#define NA    90
#define DET   729
#define NPIX  (IMG*IMG)
#define HW    514            // halo'd NHWC width/height
#define QW    514            // quad image width
#define HBELEMS (HW*HW*32)   // elems per halo'd NHWC bf16 buffer

typedef __attribute__((ext_vector_type(8))) short     bf16x8;
typedef __attribute__((ext_vector_type(8))) unsigned short ushort8;
typedef __attribute__((ext_vector_type(4))) float     f32x4;

__device__ __forceinline__ unsigned short f2b(float f) {
    unsigned int u = __builtin_bit_cast(unsigned int, f);
    return (unsigned short)((u + 0x7FFFu + ((u >> 16) & 1u)) >> 16);
}
__device__ __forceinline__ float b2f(unsigned short h) {
    return __builtin_bit_cast(float, (unsigned int)h << 16);
}

// ---------------- prep0: trig (blk 0) + f32x4 quad image (blks 1..1033) + sino zero (rest) ----------------
__global__ void prep0_k(const float* __restrict__ theta, const float* __restrict__ img,
                        float* __restrict__ trig, float4* __restrict__ quad4,
                        float* __restrict__ sino) {
    if (blockIdx.x == 0) {
        int i = threadIdx.x;
        if (i < NA) {
            float t = theta[i];
            trig[2*i]   = cosf(t);
            trig[2*i+1] = sinf(t);
        }
        return;
    }
    if (blockIdx.x <= 1033) {
        int q = (blockIdx.x - 1) * 256 + threadIdx.x;
        if (q >= QW*QW) return;
        int qy = q / QW, qx = q - qy*QW;
        auto val = [&](int r, int c) -> float {
            return (r >= 1 && r <= 512 && c >= 1 && c <= 512) ? img[((r-1) << 9) + (c-1)] : 0.f;
        };
        quad4[q] = make_float4(val(qy, qx), val(qy, qx+1), val(qy+1, qx), val(qy+1, qx+1));
        return;
    }
    int z = (blockIdx.x - 1034) * 256 + threadIdx.x;
    if (z < NA*DET) sino[z] = 0.f;
}

// ---------------- radon forward: f32x4 ring tile, maskless clamped loop ----------------
__global__ __launch_bounds__(256) void radon_tile_k(const float4* __restrict__ quad4,
        const float* __restrict__ trig, float* __restrict__ sino) {
    __shared__ float4 tl4[1226];
    int b  = blockIdx.x;
    int tq = b % 289;
    int g  = b / 289;                  // angle group: angles 4g..4g+3
    int tx = tq % 17, ty = tq / 17;
    int X0 = tx*32, Y0 = ty*32;        // quad-space tile origin
    int tid = threadIdx.x;

    for (int e = tid; e < 1226; e += 256) {
        float4 v = make_float4(0.f, 0.f, 0.f, 0.f);
        int r = e / 35, c = e - r*35;                 // e=1225 -> r=35: stays zero
        if (r >= 1 && r <= 32 && c >= 1 && c <= 32) {
            int gy = Y0 + r - 1, gx = X0 + c - 1;
            if (gy < QW && gx < QW) v = quad4[gy*QW + gx];
        }
        tl4[e] = v;
    }
    __syncthreads();

    int w = tid >> 6, lane = tid & 63;
    int a = g*4 + w;
    if (a >= NA) return;
    float cs = trig[2*a], sn = trig[2*a+1];   // sn >= 0 for theta in [0,pi)

    float fX0 = (float)X0 - 1.0f;      // px valid in [fX0, fX0+32)
    float fY0 = (float)Y0 - 1.0f;

    float cx0 = fX0 - 255.5f, cx1 = cx0 + 32.0f;
    float cy0 = fY0 - 255.5f, cy1 = cy0 + 32.0f;
    float sdmin = fminf(cx0*cs, cx1*cs) + fminf(cy0*sn, cy1*sn);
    float sdmax = fmaxf(cx0*cs, cx1*cs) + fmaxf(cy0*sn, cy1*sn);
    int dmin = (int)ceilf(sdmin + 364.0f) - 1; if (dmin < 0) dmin = 0;
    int dmax = (int)floorf(sdmax + 364.0f) + 1; if (dmax > DET-1) dmax = DET-1;
    int d = dmin + lane;
    if (d > dmax) return;

    float sd = (float)d - 364.0f;
    float bx = 255.5f + sd*cs, by = 255.5f + sd*sn;
    float lo = -365.0f, hi = 365.0f;
    if (sn > 1e-7f) {
        float inv = 1.0f / sn;
        lo = (bx - (fX0 + 32.0f)) * inv;
        hi = (bx - fX0) * inv;
    } else if (bx < fX0 || bx >= fX0 + 32.0f) return;
    if (fabsf(cs) > 1e-7f) {
        float inv = 1.0f / cs;
        float s1 = (fY0 - by) * inv, s2 = (fY0 + 32.0f - by) * inv;
        lo = fmaxf(lo, fminf(s1, s2));
        hi = fminf(hi, fmaxf(s1, s2));
    } else if (by < fY0 || by >= fY0 + 32.0f) return;
    int jlo = (int)ceilf(lo + 364.0f) - 1; if (jlo < 0) jlo = 0;
    int jhi = (int)floorf(hi + 364.0f) + 1; if (jhi > DET-1) jhi = DET-1;
    if (jlo > jhi) return;

    float sj = (float)jlo - 364.0f;
    float px2 = bx - sj*sn - fX0 + 1.0f;
    float py2 = by + sj*cs - fY0 + 1.0f;
    float acc = 0.f;
    #pragma unroll 2
    for (int j = jlo; j <= jhi; ++j) {
        float fpx = floorf(px2), fpy = floorf(py2);
        int ix = (int)fpx, iy = (int)fpy;
        float fx = px2 - fpx, fy = py2 - fpy;
        unsigned ba = ((unsigned)(iy*35 + ix)) * 16u;
        if (ba > 19584u) ba = 19600u;              // zero slot: contribution exactly 0
        float4 q = *(const float4*)((const char*)tl4 + ba);
        float top = fmaf(fx, q.y - q.x, q.x);
        float bot = fmaf(fx, q.w - q.z, q.z);
        acc += fmaf(fy, bot - top, top);
        px2 -= sn; py2 += cs;
    }
    if (acc != 0.f) atomicAdd(&sino[a*DET + d], acc);
}

// ---------------- ramp filter + subtract measurement + pair pack (fused, 1 block/angle) ----------------
__global__ __launch_bounds__(768) void filter_k(const float* __restrict__ sino,
        const float* __restrict__ meas, float2* __restrict__ dpair) {
    __shared__ float prow[DET + 2*728];
    __shared__ float invsq[364];
    __shared__ float drow[DET];
    int a = blockIdx.x;
    for (int t = threadIdx.x; t < DET + 2*728; t += 768)
        prow[t] = (t >= 728 && t < 728 + DET) ? sino[a*DET + (t - 728)] : 0.f;
    const float cc = -2.0f / (3.14159265358979323846f * 3.14159265358979323846f);
    if (threadIdx.x < 364) {
        float dlt = (float)(2*threadIdx.x + 1);
        invsq[threadIdx.x] = cc / (dlt * dlt);
    }
    __syncthreads();
    const float scale = 3.14159265358979323846f / 180.0f;  // pi/(2*90)
    int i = threadIdx.x;
    if (i < DET) {
        const float* p = prow + 728 + i;
        float acc = 0.5f * p[0];
        #pragma unroll 4
        for (int k = 0; k < 364; k++) {
            int dlt = 2*k + 1;
            acc += (p[-dlt] + p[dlt]) * invsq[k];
        }
        drow[i] = acc * scale - meas[a*DET + i];
    }
    __syncthreads();
    if (i < DET)
        dpair[a*DET + i] = make_float2(drow[i], (i < DET-1) ? drow[i+1] : 0.f);
}

// ---------------- backprojection fused with x_input = x - lambda*bp ----------------
__global__ __launch_bounds__(256) void backproj_k(const float2* __restrict__ pair,
        const float* __restrict__ trig, const float* __restrict__ x,
        const float* __restrict__ lam, float* __restrict__ xin) {
    int pix = blockIdx.x * 256 + threadIdx.x;
    float X = (float)(pix & 511) - 255.5f;
    float Y = (float)(pix >> 9) - 255.5f;
    float acc = 0.f;
    for (int a = 0; a < NA; a++) {
        float pos = X*trig[2*a] + Y*trig[2*a+1] + 364.0f;
        if (pos >= 0.f && pos <= 728.f) {
            int i0 = (int)pos;
            if (i0 > 727) i0 = 727;
            float w = pos - (float)i0;
            float2 p = pair[a*DET + i0];
            acc += p.x + w*(p.y - p.x);
        }
    }
    xin[pix] = x[pix] - lam[0] * acc;
}

// ---------------- prep1: halo zeroing + convM weights + convG padded weights ----------------
__global__ void prep1_k(unsigned short* __restrict__ hb0, size_t hbstride_elems,
                        const float* __restrict__ w0, const float* __restrict__ w1,
                        const float* __restrict__ w2, const float* __restrict__ w3,
                        const float* __restrict__ wg4,
                        unsigned short* __restrict__ wbuf) {
    int t = blockIdx.x * 256 + threadIdx.x;
    if (t < 4*2052) {
        int b = t / 2052, r = t - b*2052;
        int py, px;
        if      (r < 514)  { py = 0;            px = r; }
        else if (r < 1028) { py = 513;          px = r - 514; }
        else if (r < 1540) { py = r - 1028 + 1; px = 0; }
        else               { py = r - 1540 + 1; px = 513; }
        unsigned short* p = hb0 + b*hbstride_elems + ((size_t)py*HW + px)*32;
        uint4 z = make_uint4(0,0,0,0);
        ((uint4*)p)[0] = z; ((uint4*)p)[1] = z; ((uint4*)p)[2] = z; ((uint4*)p)[3] = z;
        return;
    }
    int tid = t - 4*2052;
    if (tid < 4*9216) {
        int L = tid / 9216, r = tid - L*9216;
        int tt = r >> 10, o = (r >> 5) & 31, i = r & 31;
        const float* s = (L == 0) ? w0 : (L == 1) ? w1 : (L == 2) ? w2 : w3;
        wbuf[tid] = f2b(s[o*288 + i*9 + tt]);
        return;
    }
    int gid = tid - 4*9216;                 // wG padded: [tap][16 oc][32 ic], oc0 real
    if (gid >= 9*512) return;
    int tt = gid / 512, r = gid - tt*512;
    int o = r >> 5, i = r & 31;
    wbuf[4*9216 + gid] = (o == 0) ? f2b(wg4[i*9 + tt]) : (unsigned short)0;
}

// ---------------- conv_D: 1 -> 32, f32 direct; writes bf16 NHWC halo'd ----------------
__global__ __launch_bounds__(256) void convD_k(const float* __restrict__ xin,
        const float* __restrict__ wD, unsigned short* __restrict__ out_nhwc) {
    int pix = blockIdx.x * 256 + threadIdx.x;
    int y = pix >> 9, x = pix & 511;
    float v[9];
    #pragma unroll
    for (int dy = -1; dy <= 1; dy++)
        #pragma unroll
        for (int dx = -1; dx <= 1; dx++) {
            int yy = y + dy, xx = x + dx;
            v[(dy+1)*3 + dx+1] = (yy >= 0 && yy < 512 && xx >= 0 && xx < 512)
                                 ? xin[(yy << 9) + xx] : 0.f;
        }
    unsigned int packed[16];
    #pragma unroll
    for (int oc = 0; oc < 32; ++oc) {
        float acc = 0.f;
        #pragma unroll
        for (int t = 0; t < 9; t++) acc = fmaf(v[t], wD[oc*9 + t], acc);
        unsigned int b = f2b(acc);
        if (oc & 1) packed[oc >> 1] |= b << 16; else packed[oc >> 1] = b;
    }
    uint4* dst = (uint4*)(out_nhwc + ((size_t)(y+1)*HW + (x+1))*32);
    dst[0] = make_uint4(packed[0],  packed[1],  packed[2],  packed[3]);
    dst[1] = make_uint4(packed[4],  packed[5],  packed[6],  packed[7]);
    dst[2] = make_uint4(packed[8],  packed[9],  packed[10], packed[11]);
    dst[3] = make_uint4(packed[12], packed[13], packed[14], packed[15]);
}

// ---------------- MFMA conv 32->32: 4-row blocked, dx-outer, XCD band swizzle ----------------
// blk -> (xcd=blk&7, idx=blk>>3): by = xcd*4 + idx/32, bx = idx%32. Each XCD owns a
// 4-block-row band (66 input rows ~ 2.2MB < 4MB XCD L2) so dy-halo re-reads are L2-local.
// MODE: 0 plain->out0 | 1 relu->out0 | 2 dual: raw->out0, softthr->out1
//       | 3 symloss: - aux(bf16 NHWC) -> s1,s2 (f32 NCHW)
template<int MODE>
__global__ __launch_bounds__(256, 4) void convM_k(const unsigned short* __restrict__ in,
        const unsigned short* __restrict__ wb,
        unsigned short* __restrict__ out0, unsigned short* __restrict__ out1,
        const float* __restrict__ thr_p,
        const unsigned short* __restrict__ aux, float* __restrict__ s1, float* __restrict__ s2) {
    int wv   = threadIdx.x >> 6;
    int lane = threadIdx.x & 63;
    int blk  = blockIdx.x;
    int xcd  = blk & 7;
    int idx  = blk >> 3;
    int by = (xcd << 2) + (idx >> 5);
    int bx = idx & 31;
    int x0 = bx*16;
    int yb = by*16 + wv*4;        // first output row of this wave
    int lpix = lane & 15;
    int k8   = (lane >> 4) * 8;

    f32x4 acc[2][4];
    #pragma unroll
    for (int ob = 0; ob < 2; ob++)
        #pragma unroll
        for (int o = 0; o < 4; o++) acc[ob][o] = (f32x4){0.f,0.f,0.f,0.f};

    const short* base = (const short*)in + ((size_t)yb*HW + (x0 + lpix))*32 + k8;

    #pragma unroll
    for (int dx = 0; dx < 3; ++dx) {
        bf16x8 A2[3][2];
        #pragma unroll
        for (int dy = 0; dy < 3; ++dy)
            #pragma unroll
            for (int ob = 0; ob < 2; ob++)
                A2[dy][ob] = *(const bf16x8*)(wb + (dy*3+dx)*1024 + (ob*16 + lpix)*32 + k8);
        #pragma unroll
        for (int r = 0; r < 6; ++r) {
            bf16x8 B = *(const bf16x8*)(base + ((size_t)r*HW + dx)*32);
            #pragma unroll
            for (int dy = 0; dy < 3; ++dy) {
                int o = r - dy;
                if (o >= 0 && o < 4) {
                    acc[0][o] = __builtin_amdgcn_mfma_f32_16x16x32_bf16(A2[dy][0], B, acc[0][o], 0,0,0);
                    acc[1][o] = __builtin_amdgcn_mfma_f32_16x16x32_bf16(A2[dy][1], B, acc[1][o], 0,0,0);
                }
            }
        }
    }

    int prow = (lane >> 4) * 4;
    float thr = (MODE == 2) ? thr_p[0] : 0.f;
    #pragma unroll
    for (int ob = 0; ob < 2; ob++)
        #pragma unroll
        for (int o = 0; o < 4; o++) {
            f32x4 a = acc[ob][o];
            if (MODE == 3) {
                size_t aoff = ((size_t)(yb+o+1)*HW + (x0 + 1 + lpix))*32 + ob*16 + prow;
                ushort4 av = *(const ushort4*)(aux + aoff);
                int pix = ((yb+o) << 9) + x0 + lpix;
                float w0v = a[0] - b2f(av.x);
                float w1v = a[1] - b2f(av.y);
                float w2v = a[2] - b2f(av.z);
                float w3v = a[3] - b2f(av.w);
                int ocb = ob*16 + prow;
                s1[(size_t)(ocb+0)*NPIX + pix] = w0v; s2[(size_t)(ocb+0)*NPIX + pix] = w0v;
                s1[(size_t)(ocb+1)*NPIX + pix] = w1v; s2[(size_t)(ocb+1)*NPIX + pix] = w1v;
                s1[(size_t)(ocb+2)*NPIX + pix] = w2v; s2[(size_t)(ocb+2)*NPIX + pix] = w2v;
                s1[(size_t)(ocb+3)*NPIX + pix] = w3v; s2[(size_t)(ocb+3)*NPIX + pix] = w3v;
            } else {
                size_t off = ((size_t)(yb+o+1)*HW + (x0 + 1 + lpix))*32 + ob*16 + prow;
                if (MODE == 1) {
                    #pragma unroll
                    for (int r2 = 0; r2 < 4; r2++) a[r2] = fmaxf(a[r2], 0.f);
                }
                *(ushort4*)(out0 + off) = make_ushort4(f2b(a[0]), f2b(a[1]), f2b(a[2]), f2b(a[3]));
                if (MODE == 2) {
                    float st[4];
                    #pragma unroll
                    for (int r2 = 0; r2 < 4; r2++)
                        st[r2] = copysignf(fmaxf(fabsf(a[r2]) - thr, 0.f), a[r2]);
                    *(ushort4*)(out1 + off) = make_ushort4(f2b(st[0]), f2b(st[1]), f2b(st[2]), f2b(st[3]));
                }
            }
        }
}

// ---------------- conv_G via MFMA: 32 -> 1 (A row 0 = wG), fused + xin; XCD band swizzle ----------------
__global__ __launch_bounds__(256) void convGM_k(const unsigned short* __restrict__ in,
        const unsigned short* __restrict__ wg,      // [tap][16][32], oc0 real
        const float* __restrict__ xin, float* __restrict__ out) {
    int wid  = threadIdx.x >> 6;
    int lane = threadIdx.x & 63;
    int blk  = blockIdx.x;
    int xcd  = blk & 7;
    int idx  = blk >> 3;
    int by = (xcd << 4) + (idx >> 3);
    int bx = idx & 7;
    int y  = by*4 + wid;
    int x0 = bx*64;
    int lpix = lane & 15;
    int k8   = (lane >> 4) * 8;

    bf16x8 A[9];
    #pragma unroll
    for (int t = 0; t < 9; t++)
        A[t] = *(const bf16x8*)(wg + t*512 + lpix*32 + k8);

    f32x4 acc[4];
    #pragma unroll
    for (int p = 0; p < 4; p++) acc[p] = (f32x4){0.f,0.f,0.f,0.f};

    const short* base = (const short*)in + ((size_t)(y+1)*HW + (x0+1) + lpix)*32 + k8;
    #pragma unroll
    for (int dy = -1; dy <= 1; dy++)
        #pragma unroll
        for (int dx = -1; dx <= 1; dx++) {
            int t = (dy+1)*3 + (dx+1);
            const short* bp = base + (dy*HW + dx)*32;
            #pragma unroll
            for (int p = 0; p < 4; p++) {
                bf16x8 B = *(const bf16x8*)(bp + p*16*32);
                acc[p] = __builtin_amdgcn_mfma_f32_16x16x32_bf16(A[t], B, acc[p], 0,0,0);
            }
        }

    if (lane < 16) {
        #pragma unroll
        for (int p = 0; p < 4; p++) {
            int pix = (y << 9) + x0 + p*16 + lane;
            out[pix] = acc[p][0] + xin[pix];
        }
    }
}

extern "C" void kernel_launch(void* const* d_in, const int* in_sizes, int n_in,
                              void* d_out, int out_size, void* d_ws, size_t ws_size,
                              hipStream_t stream) {
    const float* x     = (const float*)d_in[0];
    const float* theta = (const float*)d_in[1];
    const float* meas  = (const float*)d_in[2];
    const float* lam   = (const float*)d_in[3];
    const float* thr   = (const float*)d_in[4];
    const float* wD    = (const float*)d_in[5];
    const float* w1f   = (const float*)d_in[6];
    const float* w2f   = (const float*)d_in[7];
    const float* w1b   = (const float*)d_in[8];
    const float* w2b   = (const float*)d_in[9];
    const float* wG    = (const float*)d_in[10];

    char* ws = (char*)d_ws;
    const size_t HBB = (size_t)HBELEMS * 2;          // bytes per halo'd bf16 buffer
    unsigned short* HB1 = (unsigned short*)(ws);
    unsigned short* HB2 = (unsigned short*)(ws + HBB);
    unsigned short* HB3 = (unsigned short*)(ws + 2*HBB);
    unsigned short* HB4 = (unsigned short*)(ws + 3*HBB);
    // radon scratch aliases: sino/dpair in HB2 (dead until h1), quad4 (4.03MB) in HB3 (dead until xf;
    // HB3 halo ring is zeroed by prep1 AFTER radon consumes quad4 — ordering is load-bearing!)
    float*  sino  = (float*)(ws + HBB);
    float2* dpair = (float2*)(ws + HBB + 524928);
    float4* quad4 = (float4*)(ws + 2*HBB);
    float* xin  = (float*)(ws + 4*HBB);
    float* trig = (float*)(ws + 4*HBB + 1048576);
    unsigned short* wbuf = (unsigned short*)(ws + 4*HBB + 1049600);
    unsigned short* wgbuf = wbuf + 4*9216;

    float* P  = (float*)d_out;        // x_pred  (NPIX)
    float* S1 = P + NPIX;             // symloss #1 (32*NPIX)
    float* S2 = S1 + 32*NPIX;         // symloss #2 (32*NPIX)

    prep0_k<<<1 + 1033 + 257, 256, 0, stream>>>(theta, x, trig, quad4, sino);
    radon_tile_k<<<289*23, 256, 0, stream>>>(quad4, trig, sino);
    filter_k<<<NA, 768, 0, stream>>>(sino, meas, dpair);
    backproj_k<<<NPIX/256, 256, 0, stream>>>(dpair, trig, x, lam, xin);
    prep1_k<<<(4*2052 + 4*9216 + 9*512 + 255)/256, 256, 0, stream>>>(HB1, HBELEMS,
                                             w1f, w2f, w1b, w2b, wG, wbuf);

    convD_k<<<NPIX/256, 256, 0, stream>>>(xin, wD, HB1);                           // x_D -> HB1 (persists)
    convM_k<1><<<1024, 256, 0, stream>>>(HB1, wbuf + 0*9216, HB2, nullptr,
                                         nullptr, nullptr, nullptr, nullptr);      // h1 -> HB2
    convM_k<2><<<1024, 256, 0, stream>>>(HB2, wbuf + 1*9216, HB3, HB4,
                                         thr, nullptr, nullptr, nullptr);          // xf -> HB3, st -> HB4
    convM_k<1><<<1024, 256, 0, stream>>>(HB4, wbuf + 2*9216, HB2, nullptr,
                                         nullptr, nullptr, nullptr, nullptr);      // h2 -> HB2
    convM_k<0><<<1024, 256, 0, stream>>>(HB2, wbuf + 3*9216, HB4, nullptr,
                                         nullptr, nullptr, nullptr, nullptr);      // xb -> HB4
    convGM_k<<<1024, 256, 0, stream>>>(HB4, wgbuf, xin, P);                        // x_pred
    convM_k<1><<<1024, 256, 0, stream>>>(HB3, wbuf + 2*9216, HB2, nullptr,
                                         nullptr, nullptr, nullptr, nullptr);      // h3 -> HB2
    convM_k<3><<<1024, 256, 0, stream>>>(HB2, wbuf + 3*9216, nullptr, nullptr,
                                         nullptr, HB1, S1, S2);                    // symloss
}